// Round 1
// baseline (1127.633 us; speedup 1.0000x reference)
//
#include <hip/hip_runtime.h>
#include <hip/hip_bf16.h>
#include <math.h>

// Problem constants
#define NN 32768          // Dd*Hh*Ww tokens per batch
#define CC 256
#define EE 6
#define HID 1024
#define TT 64             // tokens per workgroup
#define NTOK 65536        // B * NN

typedef __attribute__((ext_vector_type(8))) short bf16x8;   // 8 bf16 = 4 VGPRs
typedef __attribute__((ext_vector_type(4))) float f32x4;

__device__ __forceinline__ unsigned short f32_bf16(float f) {
  unsigned u = __builtin_bit_cast(unsigned, f);
  u += 0x7FFFu + ((u >> 16) & 1u);          // RNE
  return (unsigned short)(u >> 16);
}

// one-time f32 -> bf16 weight conversion into workspace
__global__ void wconv(const float* __restrict__ w1, const float* __restrict__ w2,
                      unsigned short* __restrict__ w1b, unsigned short* __restrict__ w2b) {
  int i = blockIdx.x * 256 + threadIdx.x;
  w1b[i] = f32_bf16(w1[i]);
  w2b[i] = f32_bf16(w2[i]);
}

__global__ __launch_bounds__(256, 2) void moe_main(
    const float* __restrict__ x, const float* __restrict__ attn,
    const float* __restrict__ gate_w, const float* __restrict__ gate_b,
    const float* __restrict__ b1, const float* __restrict__ b2,
    const unsigned short* __restrict__ w1b, const unsigned short* __restrict__ w2b,
    float* __restrict__ out) {
  // LDS: X tile (bf16, swizzled), Hd tile (bf16, swizzled; aliased as gate-reduce
  // scratch in the prologue), gate weights, per-token expert mask.
  __shared__ unsigned char ldsx[TT * CC * 2];   // 32 KB
  __shared__ unsigned char ldsh[TT * 256 * 2];  // 32 KB
  __shared__ float gwS[EE * CC];                // 6 KB
  __shared__ float maskS[EE * TT];              // 1.5 KB

  const int tid  = threadIdx.x;
  const int lane = tid & 63;
  const int wv   = tid >> 6;        // wave id 0..3
  const int lr   = lane & 15;       // MFMA row/col selector
  const int lg   = lane >> 4;       // MFMA k-group / D row group

  const int token0 = blockIdx.x * TT;
  const int bIdx   = token0 >> 15;          // batch (NN = 32768)
  const int n0     = token0 & (NN - 1);     // tile never crosses batch (64 | 32768)

  // ---------- load gate weights ----------
  for (int i = tid; i < EE * CC; i += 256) gwS[i] = gate_w[i];
  __syncthreads();

  // ---------- stage X (f32 -> bf16, swizzled) + gate partial dots ----------
  float* gred = (float*)ldsh;   // [4][64][6] partial gate sums
  {
    float gp[EE] = {0.f, 0.f, 0.f, 0.f, 0.f, 0.f};
    const size_t xbase = ((size_t)bIdx * CC + wv * 64) * NN + n0 + lane;
    const unsigned xorl = (unsigned)(lane & 7) << 4;
    #pragma unroll 8
    for (int i = 0; i < 64; ++i) {
      float xv = x[xbase + (size_t)i * NN];           // coalesced over lanes (n)
      int c = wv * 64 + i;
      *(unsigned short*)(ldsx + ((((unsigned)lane * 512u) | ((unsigned)(c * 2))) ^ xorl)) =
          f32_bf16(xv);
      #pragma unroll
      for (int e = 0; e < EE; ++e) gp[e] += xv * gwS[e * CC + c];
    }
    #pragma unroll
    for (int e = 0; e < EE; ++e) gred[(wv * 64 + lane) * EE + e] = gp[e];
  }
  __syncthreads();

  // ---------- gating: f32 softmax + top-3 (selection on exact logits) ----------
  if (tid < 64) {   // exactly wave 0, uniform
    float g[EE];
    #pragma unroll
    for (int e = 0; e < EE; ++e)
      g[e] = gred[(0 * 64 + tid) * EE + e] + gred[(1 * 64 + tid) * EE + e] +
             gred[(2 * 64 + tid) * EE + e] + gred[(3 * 64 + tid) * EE + e];
    float aw = attn[token0 + tid];
    float m = -1e30f;
    #pragma unroll
    for (int e = 0; e < EE; ++e) { g[e] = (g[e] + gate_b[e]) * aw; m = fmaxf(m, g[e]); }
    float ex[EE], s = 0.f;
    #pragma unroll
    for (int e = 0; e < EE; ++e) { ex[e] = expf(g[e] - m); s += ex[e]; }
    // top-3 on logits (monotone with softmax); strict > keeps earliest index like lax.top_k
    int i1 = 0; float v1 = g[0];
    #pragma unroll
    for (int e = 1; e < EE; ++e) if (g[e] > v1) { v1 = g[e]; i1 = e; }
    int i2 = -1; float v2 = -3.4e38f;
    #pragma unroll
    for (int e = 0; e < EE; ++e) if (e != i1 && g[e] > v2) { v2 = g[e]; i2 = e; }
    int i3 = -1; float v3 = -3.4e38f;
    #pragma unroll
    for (int e = 0; e < EE; ++e) if (e != i1 && e != i2 && g[e] > v3) { v3 = g[e]; i3 = e; }
    float inv = 1.f / s;
    #pragma unroll
    for (int e = 0; e < EE; ++e)
      maskS[e * TT + tid] = (e == i1 || e == i2 || e == i3) ? ex[e] * inv : 0.f;
  }
  __syncthreads();

  // ---------- main loop: per expert, per 256-wide HID superchunk ----------
  f32x4 oacc[4][4];   // persistent output accumulators: o[64 t][wv*64 + 64 c]
  #pragma unroll
  for (int fm = 0; fm < 4; ++fm)
    #pragma unroll
    for (int fc = 0; fc < 4; ++fc) oacc[fm][fc] = (f32x4){0.f, 0.f, 0.f, 0.f};

  const unsigned xorl = (unsigned)(lr & 7) << 4;   // row&7 == lr&7 for all A-frag rows
  unsigned arow[4];
  #pragma unroll
  for (int fm = 0; fm < 4; ++fm) arow[fm] = (unsigned)((fm * 16 + lr) * 512);

  #pragma unroll 1
  for (int e = 0; e < EE; ++e) {
    #pragma unroll 1
    for (int sc = 0; sc < 4; ++sc) {
      // ---- GEMM1: Hd[64 t][this wave's 64 h], K = 256 (c) ----
      f32x4 hacc[4][4];
      #pragma unroll
      for (int fm = 0; fm < 4; ++fm)
        #pragma unroll
        for (int fn = 0; fn < 4; ++fn) hacc[fm][fn] = (f32x4){0.f, 0.f, 0.f, 0.f};
      const unsigned short* w1p =
          w1b + ((size_t)(e * HID + sc * 256 + wv * 64 + lr)) * CC + lg * 8;
      #pragma unroll
      for (int ks = 0; ks < 8; ++ks) {
        bf16x8 a[4];
        unsigned kb = ((unsigned)(ks * 64 + lg * 16)) ^ xorl;
        #pragma unroll
        for (int fm = 0; fm < 4; ++fm)
          a[fm] = *(const bf16x8*)(ldsx + (arow[fm] + kb));
        #pragma unroll
        for (int fn = 0; fn < 4; ++fn) {
          bf16x8 bf = *(const bf16x8*)(w1p + fn * 16 * CC + ks * 32);  // L2-resident
          #pragma unroll
          for (int fm = 0; fm < 4; ++fm)
            hacc[fm][fn] =
                __builtin_amdgcn_mfma_f32_16x16x32_bf16(a[fm], bf, hacc[fm][fn], 0, 0, 0);
        }
      }
      // ---- bias + exact-erf GELU + mask fold, write bf16 Hd to swizzled LDS ----
      #pragma unroll
      for (int fn = 0; fn < 4; ++fn) {
        float b1v = b1[e * HID + sc * 256 + wv * 64 + fn * 16 + lr];
        #pragma unroll
        for (int fm = 0; fm < 4; ++fm) {
          #pragma unroll
          for (int r = 0; r < 4; ++r) {
            int t = fm * 16 + lg * 4 + r;
            float v = hacc[fm][fn][r] + b1v;
            v = 0.5f * v * (1.f + erff(v * 0.70710678118654752f));
            v *= maskS[e * TT + t];
            unsigned ha = ((unsigned)(t * 512 + (wv * 64 + fn * 16 + lr) * 2)) ^
                          (((unsigned)(t & 7)) << 4);
            *(unsigned short*)(ldsh + ha) = f32_bf16(v);
          }
        }
      }
      __syncthreads();
      // ---- GEMM2: oacc += Hd[64][256] @ w2[e][c][h]^T (wave's 64 c) ----
      const unsigned short* w2p =
          w2b + ((size_t)(e * CC + wv * 64 + lr)) * HID + sc * 256 + lg * 8;
      #pragma unroll
      for (int ks = 0; ks < 8; ++ks) {
        bf16x8 a[4];
        unsigned kb = ((unsigned)(ks * 64 + lg * 16)) ^ xorl;
        #pragma unroll
        for (int fm = 0; fm < 4; ++fm)
          a[fm] = *(const bf16x8*)(ldsh + (arow[fm] + kb));
        #pragma unroll
        for (int fc = 0; fc < 4; ++fc) {
          bf16x8 bf = *(const bf16x8*)(w2p + fc * 16 * HID + ks * 32);
          #pragma unroll
          for (int fm = 0; fm < 4; ++fm)
            oacc[fm][fc] =
                __builtin_amdgcn_mfma_f32_16x16x32_bf16(a[fm], bf, oacc[fm][fc], 0, 0, 0);
        }
      }
      __syncthreads();   // protect ldsh before next superchunk overwrites it
    }
  }

  // ---------- epilogue: + sum_e mask_e * b2[e][c], store f32 ----------
  float b2c[4][EE];
  #pragma unroll
  for (int fc = 0; fc < 4; ++fc)
    #pragma unroll
    for (int e = 0; e < EE; ++e) b2c[fc][e] = b2[e * CC + wv * 64 + fc * 16 + lr];

  const size_t obase = ((size_t)bIdx * CC) * NN + n0;
  #pragma unroll
  for (int fm = 0; fm < 4; ++fm) {
    #pragma unroll
    for (int r = 0; r < 4; ++r) {
      int t = fm * 16 + lg * 4 + r;
      float msk[EE];
      #pragma unroll
      for (int e = 0; e < EE; ++e) msk[e] = maskS[e * TT + t];
      #pragma unroll
      for (int fc = 0; fc < 4; ++fc) {
        int c = wv * 64 + fc * 16 + lr;
        float v = oacc[fm][fc][r];
        #pragma unroll
        for (int e = 0; e < EE; ++e) v += msk[e] * b2c[fc][e];
        out[obase + (size_t)c * NN + t] = v;
      }
    }
  }
}

extern "C" void kernel_launch(void* const* d_in, const int* in_sizes, int n_in,
                              void* d_out, int out_size, void* d_ws, size_t ws_size,
                              hipStream_t stream) {
  const float* x      = (const float*)d_in[0];
  const float* attn   = (const float*)d_in[1];
  const float* gate_w = (const float*)d_in[2];
  const float* gate_b = (const float*)d_in[3];
  const float* w1     = (const float*)d_in[4];
  const float* b1     = (const float*)d_in[5];
  const float* w2     = (const float*)d_in[6];
  const float* b2     = (const float*)d_in[7];
  float* out = (float*)d_out;

  unsigned short* w1b = (unsigned short*)d_ws;                  // 3 MB
  unsigned short* w2b = w1b + (size_t)EE * HID * CC;            // 3 MB

  wconv<<<(EE * HID * CC) / 256, 256, 0, stream>>>(w1, w2, w1b, w2b);
  moe_main<<<NTOK / TT, 256, 0, stream>>>(x, attn, gate_w, gate_b, b1, b2, w1b, w2b, out);
}

// Round 2
// 800.058 us; speedup vs baseline: 1.4094x; 1.4094x over previous
//
#include <hip/hip_runtime.h>
#include <hip/hip_bf16.h>
#include <math.h>

// Problem constants
#define NN 32768          // Dd*Hh*Ww tokens per batch
#define CC 256
#define EE 6
#define HID 1024
#define TT 64             // tokens per workgroup
#define NTOK 65536        // B * NN

typedef __attribute__((ext_vector_type(8))) short bf16x8;   // 8 bf16 = 4 VGPRs
typedef __attribute__((ext_vector_type(4))) float f32x4;
typedef __attribute__((ext_vector_type(4))) unsigned int u32x4;
typedef __attribute__((ext_vector_type(2))) unsigned int u32x2;

__device__ __forceinline__ unsigned short f32_bf16(float f) {
  unsigned u = __builtin_bit_cast(unsigned, f);
  u += 0x7FFFu + ((u >> 16) & 1u);          // RNE
  return (unsigned short)(u >> 16);
}

// tanh-form GELU via sigmoid identity: 0.5v(1+tanh(u)) = v * sigmoid(2u)
//   2u*log2e = 2.3021181819*v*(1+0.044715 v^2);  g = v * rcp(1 + exp2(-that))
// max abs deviation from exact erf-GELU ~1e-3; saturates cleanly (no inf*0).
__device__ __forceinline__ float fast_gelu(float v) {
  float s = v * v;
  float a = v * -2.3021181819f;
  float m = a * 0.044715f;
  float nu = __builtin_fmaf(m, s, a);       // -(2u*log2e)
  float z = __builtin_amdgcn_exp2f(nu);
  return v * __builtin_amdgcn_rcpf(1.0f + z);
}

// one-time f32 -> bf16 weight conversion into workspace
__global__ void wconv(const float* __restrict__ w1, const float* __restrict__ w2,
                      unsigned short* __restrict__ w1b, unsigned short* __restrict__ w2b) {
  int i = blockIdx.x * 256 + threadIdx.x;
  w1b[i] = f32_bf16(w1[i]);
  w2b[i] = f32_bf16(w2[i]);
}

// Swapped-operand design: GEMM1 computes Hd^T[h][t] = w1 x X^T, GEMM2 computes
// O^T[c][t] = w2 x Hd^T.  A-frags (weights) stream from L2; B-frags (X / Hd)
// are contiguous 16B LDS rows with a (t&31)<<4 XOR swizzle.  D-fragments hold
// 4 consecutive h (resp. c) per lane -> packed b64 LDS writes after GELU.
__global__ __launch_bounds__(256, 2) void moe_main(
    const float* __restrict__ x, const float* __restrict__ attn,
    const float* __restrict__ gate_w, const float* __restrict__ gate_b,
    const float* __restrict__ b1, const float* __restrict__ b2,
    const unsigned short* __restrict__ w1b, const unsigned short* __restrict__ w2b,
    float* __restrict__ out) {
  __shared__ unsigned char xs[TT * CC * 2];   // 32 KB  X tile [t][c] bf16, swizzled
  __shared__ unsigned char hs[TT * 256 * 2];  // 32 KB  Hd tile [t][h'] bf16, swizzled
  __shared__ float gwS[EE * CC];              // 6 KB
  __shared__ float maskS[EE * TT];            // 1.5 KB

  const int tid  = threadIdx.x;
  const int lane = tid & 63;
  const int wv   = tid >> 6;        // wave id 0..3
  const int lr   = lane & 15;
  const int lg   = lane >> 4;

  const int token0 = blockIdx.x * TT;
  const int bIdx   = token0 >> 15;          // batch (NN = 32768)
  const int n0     = token0 & (NN - 1);

  for (int i = tid; i < EE * CC; i += 256) gwS[i] = gate_w[i];
  __syncthreads();

  // ---------- stage X (f32 -> bf16, [t][c] rows, swizzled) + gate partials ----------
  float* gred = (float*)hs;   // [4][64][6] partial gate sums (hs is free here)
  {
    float gp[EE] = {0.f, 0.f, 0.f, 0.f, 0.f, 0.f};
    const int t = lane;                         // this lane owns token row t
    const unsigned trow = (unsigned)t * 512u;
    const unsigned tsw  = ((unsigned)(t & 31)) << 4;
    const size_t xbase = ((size_t)bIdx * CC + wv * 64) * NN + n0 + lane;
    #pragma unroll 1
    for (int c8 = 0; c8 < 8; ++c8) {
      float xv[8];
      #pragma unroll
      for (int j = 0; j < 8; ++j)
        xv[j] = x[xbase + (size_t)(c8 * 8 + j) * NN];   // coalesced over lanes
      #pragma unroll
      for (int j = 0; j < 8; ++j) {
        int c = wv * 64 + c8 * 8 + j;
        #pragma unroll
        for (int e = 0; e < EE; ++e) gp[e] = __builtin_fmaf(xv[j], gwS[e * CC + c], gp[e]);
      }
      u32x4 pk;
      #pragma unroll
      for (int q = 0; q < 4; ++q)
        pk[q] = (unsigned)f32_bf16(xv[2 * q]) | ((unsigned)f32_bf16(xv[2 * q + 1]) << 16);
      unsigned byteo = trow + (((unsigned)((wv * 64 + c8 * 8) * 2)) ^ tsw);
      *(u32x4*)(xs + byteo) = pk;
    }
    #pragma unroll
    for (int e = 0; e < EE; ++e) gred[(wv * 64 + lane) * EE + e] = gp[e];
  }
  __syncthreads();

  // ---------- gating: f32 softmax + top-3 (selection on exact logits) ----------
  if (tid < 64) {
    float g[EE];
    #pragma unroll
    for (int e = 0; e < EE; ++e)
      g[e] = gred[(0 * 64 + tid) * EE + e] + gred[(1 * 64 + tid) * EE + e] +
             gred[(2 * 64 + tid) * EE + e] + gred[(3 * 64 + tid) * EE + e];
    float aw = attn[token0 + tid];
    float m = -1e30f;
    #pragma unroll
    for (int e = 0; e < EE; ++e) { g[e] = (g[e] + gate_b[e]) * aw; m = fmaxf(m, g[e]); }
    float ex[EE], s = 0.f;
    #pragma unroll
    for (int e = 0; e < EE; ++e) { ex[e] = expf(g[e] - m); s += ex[e]; }
    int i1 = 0; float v1 = g[0];
    #pragma unroll
    for (int e = 1; e < EE; ++e) if (g[e] > v1) { v1 = g[e]; i1 = e; }
    int i2 = -1; float v2 = -3.4e38f;
    #pragma unroll
    for (int e = 0; e < EE; ++e) if (e != i1 && g[e] > v2) { v2 = g[e]; i2 = e; }
    int i3 = -1; float v3 = -3.4e38f;
    #pragma unroll
    for (int e = 0; e < EE; ++e) if (e != i1 && e != i2 && g[e] > v3) { v3 = g[e]; i3 = e; }
    float inv = 1.f / s;
    #pragma unroll
    for (int e = 0; e < EE; ++e)
      maskS[e * TT + tid] = (e == i1 || e == i2 || e == i3) ? ex[e] * inv : 0.f;
  }
  __syncthreads();

  // ---------- main loop ----------
  f32x4 oacc[4][4];   // O^T accum: c = wv*64+fm*16+lg*4+r, t = fn*16+lr
  #pragma unroll
  for (int fm = 0; fm < 4; ++fm)
    #pragma unroll
    for (int fn = 0; fn < 4; ++fn) oacc[fm][fn] = (f32x4){0.f, 0.f, 0.f, 0.f};

  unsigned trowA[4], tswA[4];
  #pragma unroll
  for (int fn = 0; fn < 4; ++fn) {
    int t = fn * 16 + lr;
    trowA[fn] = (unsigned)t * 512u;
    tswA[fn]  = ((unsigned)(t & 31)) << 4;
  }

  #pragma unroll 1
  for (int e = 0; e < EE; ++e) {
    #pragma unroll 1
    for (int sc = 0; sc < 4; ++sc) {
      // ---- GEMM1: Hd^T[h][t], A = w1 rows (global/L2), B = X rows (LDS) ----
      f32x4 hacc[4][4];
      #pragma unroll
      for (int fm = 0; fm < 4; ++fm)
        #pragma unroll
        for (int fn = 0; fn < 4; ++fn) hacc[fm][fn] = (f32x4){0.f, 0.f, 0.f, 0.f};
      const unsigned short* w1p =
          w1b + ((size_t)(e * HID + sc * 256 + wv * 64 + lr)) * CC + lg * 8;
      #pragma unroll
      for (int ks = 0; ks < 8; ++ks) {
        bf16x8 af[4], bx[4];
        #pragma unroll
        for (int fm = 0; fm < 4; ++fm)
          af[fm] = *(const bf16x8*)(w1p + fm * 16 * CC + ks * 32);
        #pragma unroll
        for (int fn = 0; fn < 4; ++fn)
          bx[fn] = *(const bf16x8*)(xs + trowA[fn] +
                                    (((unsigned)(ks * 64 + lg * 16)) ^ tswA[fn]));
        #pragma unroll
        for (int fn = 0; fn < 4; ++fn)
          #pragma unroll
          for (int fm = 0; fm < 4; ++fm)
            hacc[fm][fn] =
                __builtin_amdgcn_mfma_f32_16x16x32_bf16(af[fm], bx[fn], hacc[fm][fn], 0, 0, 0);
      }
      // ---- bias + GELU + mask, packed b64 writes into hs[t][h'] ----
      {
        f32x4 b1v[4];
        #pragma unroll
        for (int fm = 0; fm < 4; ++fm)
          b1v[fm] = *(const f32x4*)&b1[e * HID + sc * 256 + wv * 64 + fm * 16 + lg * 4];
        #pragma unroll
        for (int fn = 0; fn < 4; ++fn) {
          float msk = maskS[e * TT + fn * 16 + lr];
          #pragma unroll
          for (int fm = 0; fm < 4; ++fm) {
            float gg[4];
            #pragma unroll
            for (int r = 0; r < 4; ++r)
              gg[r] = fast_gelu(hacc[fm][fn][r] + b1v[fm][r]) * msk;
            u32x2 pk;
            pk[0] = (unsigned)f32_bf16(gg[0]) | ((unsigned)f32_bf16(gg[1]) << 16);
            pk[1] = (unsigned)f32_bf16(gg[2]) | ((unsigned)f32_bf16(gg[3]) << 16);
            unsigned byteo = trowA[fn] +
                (((unsigned)((wv * 64 + fm * 16 + lg * 4) * 2)) ^ tswA[fn]);
            *(u32x2*)(hs + byteo) = pk;
          }
        }
      }
      __syncthreads();
      // ---- GEMM2: O^T += w2 x Hd^T, A = w2 rows (global/L2), B = Hd rows (LDS) ----
      const unsigned short* w2p =
          w2b + ((size_t)(e * CC + wv * 64 + lr)) * HID + sc * 256 + lg * 8;
      #pragma unroll
      for (int ks = 0; ks < 8; ++ks) {
        bf16x8 af[4], bh[4];
        #pragma unroll
        for (int fm = 0; fm < 4; ++fm)
          af[fm] = *(const bf16x8*)(w2p + fm * 16 * HID + ks * 32);
        #pragma unroll
        for (int fn = 0; fn < 4; ++fn)
          bh[fn] = *(const bf16x8*)(hs + trowA[fn] +
                                    (((unsigned)(ks * 64 + lg * 16)) ^ tswA[fn]));
        #pragma unroll
        for (int fn = 0; fn < 4; ++fn)
          #pragma unroll
          for (int fm = 0; fm < 4; ++fm)
            oacc[fm][fn] =
                __builtin_amdgcn_mfma_f32_16x16x32_bf16(af[fm], bh[fn], oacc[fm][fn], 0, 0, 0);
      }
      __syncthreads();   // protect hs before next superchunk overwrites it
    }
  }

  // ---------- epilogue: += sum_e mask[e][t] * b2[e][c], then store ----------
  #pragma unroll
  for (int e = 0; e < EE; ++e) {
    float msk[4];
    #pragma unroll
    for (int fn = 0; fn < 4; ++fn) msk[fn] = maskS[e * TT + fn * 16 + lr];
    #pragma unroll
    for (int fm = 0; fm < 4; ++fm) {
      f32x4 b2v = *(const f32x4*)&b2[e * CC + wv * 64 + fm * 16 + lg * 4];
      #pragma unroll
      for (int fn = 0; fn < 4; ++fn)
        #pragma unroll
        for (int r = 0; r < 4; ++r)
          oacc[fm][fn][r] = __builtin_fmaf(msk[fn], b2v[r], oacc[fm][fn][r]);
    }
  }
  const size_t obase = ((size_t)bIdx * CC) * NN + n0;
  #pragma unroll
  for (int fm = 0; fm < 4; ++fm) {
    #pragma unroll
    for (int fn = 0; fn < 4; ++fn) {
      int t = fn * 16 + lr;
      #pragma unroll
      for (int r = 0; r < 4; ++r) {
        int c = wv * 64 + fm * 16 + lg * 4 + r;
        out[obase + (size_t)c * NN + t] = oacc[fm][fn][r];
      }
    }
  }
}

extern "C" void kernel_launch(void* const* d_in, const int* in_sizes, int n_in,
                              void* d_out, int out_size, void* d_ws, size_t ws_size,
                              hipStream_t stream) {
  const float* x      = (const float*)d_in[0];
  const float* attn   = (const float*)d_in[1];
  const float* gate_w = (const float*)d_in[2];
  const float* gate_b = (const float*)d_in[3];
  const float* w1     = (const float*)d_in[4];
  const float* b1     = (const float*)d_in[5];
  const float* w2     = (const float*)d_in[6];
  const float* b2     = (const float*)d_in[7];
  float* out = (float*)d_out;

  unsigned short* w1b = (unsigned short*)d_ws;                  // 3 MB
  unsigned short* w2b = w1b + (size_t)EE * HID * CC;            // 3 MB

  wconv<<<(EE * HID * CC) / 256, 256, 0, stream>>>(w1, w2, w1b, w2b);
  moe_main<<<NTOK / TT, 256, 0, stream>>>(x, attn, gate_w, gate_b, b1, b2, w1b, w2b, out);
}